// Round 5
// baseline (239.181 us; speedup 1.0000x reference)
//
#include <hip/hip_runtime.h>
#include <cstdint>
#include <cmath>

typedef unsigned short BF16;
typedef __attribute__((ext_vector_type(8))) short short8;
typedef __attribute__((ext_vector_type(4))) float f32x4;
typedef __attribute__((ext_vector_type(16))) float f32x16;
typedef __attribute__((ext_vector_type(2))) unsigned int uint2v;
typedef __attribute__((ext_vector_type(4))) unsigned int uint4v;

#define S_LEN 4096
#define DMODEL 512
#define NHEAD 8
#define DHEAD 64
#define BS 2

__device__ __forceinline__ BF16 f2bf(float f) {
  union { float f; uint32_t u; } v; v.f = f;
  uint32_t r = (v.u + 0x7FFFu + ((v.u >> 16) & 1u)) >> 16;
  return (BF16)r;
}

__device__ __forceinline__ unsigned cvtpk(float a, float b) {
  unsigned r;
  asm volatile("v_cvt_pk_bf16_f32 %0, %1, %2" : "=v"(r) : "v"(a), "v"(b));
  return r;
}

// value held by lane l^32 (permlane32_swap: vdst'=[lo|src_lo], vsrc'=[dst_hi|hi])
__device__ __forceinline__ float partner32(float x, int hi) {
  unsigned a = __float_as_uint(x), b = a;
  uint2v r = __builtin_amdgcn_permlane32_swap(a, b, false, false);
  return __uint_as_float(hi ? r[0] : r[1]);
}

// a' = [a_lo | b_lo], b' = [a_hi | b_hi]
__device__ __forceinline__ void pl32(unsigned &a, unsigned &b) {
  uint2v r = __builtin_amdgcn_permlane32_swap(a, b, false, false);
  a = r[0]; b = r[1];
}

__device__ __forceinline__ void gload16(const void* g, void* lds) {
  __builtin_amdgcn_global_load_lds(
      (const __attribute__((address_space(1))) void*)g,
      (__attribute__((address_space(3))) void*)lds, 16, 0, 0);
}

#define MAX3(a, b, c) fmaxf(fmaxf((a), (b)), (c))

// ---------------- convert x: fp32 -> bf16 ----------------
__global__ __launch_bounds__(256) void cvt_x_k(const float* __restrict__ x,
                                               BF16* __restrict__ xb) {
  int i = blockIdx.x * 256 + threadIdx.x;
  float4 v = reinterpret_cast<const float4*>(x)[i];
  ushort4 o;
  o.x = f2bf(v.x); o.y = f2bf(v.y); o.z = f2bf(v.z); o.w = f2bf(v.w);
  reinterpret_cast<ushort4*>(xb)[i] = o;
}

// ------------- transpose + convert: W (K x N) fp32 -> Wt (N x K) bf16 -------------
__global__ __launch_bounds__(256) void tr_cvt_k(const float* __restrict__ W,
                                                BF16* __restrict__ Wt,
                                                int K, int N) {
  __shared__ float t[32][33];
  int n0 = blockIdx.x * 32, k0 = blockIdx.y * 32;
  int tx = threadIdx.x & 31, ty = threadIdx.x >> 5;
#pragma unroll
  for (int i = 0; i < 4; ++i)
    t[ty + 8 * i][tx] = W[(size_t)(k0 + ty + 8 * i) * N + n0 + tx];
  __syncthreads();
#pragma unroll
  for (int i = 0; i < 4; ++i)
    Wt[(size_t)(n0 + ty + 8 * i) * K + k0 + tx] = f2bf(t[tx][ty + 8 * i]);
}

// ---------------- GEMM: C(128x128 tile) = A(M x 512) * Bt(N x 512)^T ----------------
template <int MODE>
__global__ __launch_bounds__(256)
void gemm_k(const BF16* __restrict__ A, const BF16* __restrict__ Bt,
            const float* __restrict__ bias,
            BF16* __restrict__ Qb, BF16* __restrict__ Kb, BF16* __restrict__ Vt,
            float* __restrict__ Out) {
  __shared__ BF16 As[128 * 64];
  __shared__ BF16 Bs[128 * 64];
  const int tid = threadIdx.x;
  const int l = tid & 63, w = tid >> 6;
  const int wm = w >> 1, wn = w & 1;
  const int bm = blockIdx.x, bn = blockIdx.y;
  f32x4 acc[4][4] = {};

  for (int kt = 0; kt < 512 / 64; ++kt) {
#pragma unroll
    for (int i = 0; i < 4; ++i) {
      int ldsoff = i * 4096 + w * 1024;
      int off = ldsoff + l * 16;
      int row = off >> 7;
      int slot = ((off >> 4) & 7) ^ (row & 7);
      gload16(A + (size_t)(bm * 128 + row) * 512 + kt * 64 + slot * 8,
              (char*)As + ldsoff);
      gload16(Bt + (size_t)(bn * 128 + row) * 512 + kt * 64 + slot * 8,
              (char*)Bs + ldsoff);
    }
    __syncthreads();
    const char* Ab = (const char*)As;
    const char* Bb = (const char*)Bs;
    short8 af[4][2], bfr[4][2];
#pragma unroll
    for (int mf = 0; mf < 4; ++mf)
#pragma unroll
      for (int kk = 0; kk < 2; ++kk) {
        int row = wm * 64 + mf * 16 + (l & 15);
        int slot = ((l >> 4) + 4 * kk) ^ (row & 7);
        af[mf][kk] = *(const short8*)(Ab + row * 128 + slot * 16);
      }
#pragma unroll
    for (int nf = 0; nf < 4; ++nf)
#pragma unroll
      for (int kk = 0; kk < 2; ++kk) {
        int row = wn * 64 + nf * 16 + (l & 15);
        int slot = ((l >> 4) + 4 * kk) ^ (row & 7);
        bfr[nf][kk] = *(const short8*)(Bb + row * 128 + slot * 16);
      }
    __builtin_amdgcn_s_setprio(1);
#pragma unroll
    for (int kk = 0; kk < 2; ++kk)
#pragma unroll
      for (int mf = 0; mf < 4; ++mf)
#pragma unroll
        for (int nf = 0; nf < 4; ++nf)
          acc[mf][nf] = __builtin_amdgcn_mfma_f32_16x16x32_bf16(
              af[mf][kk], bfr[nf][kk], acc[mf][nf], 0, 0, 0);
    __builtin_amdgcn_s_setprio(0);
    __syncthreads();
  }

#pragma unroll
  for (int mf = 0; mf < 4; ++mf)
#pragma unroll
    for (int nf = 0; nf < 4; ++nf)
#pragma unroll
      for (int r = 0; r < 4; ++r) {
        int row = bm * 128 + wm * 64 + mf * 16 + ((l >> 4) << 2) + r;
        int col = bn * 128 + wn * 64 + nf * 16 + (l & 15);
        float v = acc[mf][nf][r] + bias[col];
        if (MODE == 0) {
          int sec = col >> 9, nl = col & 511;
          int h = nl >> 6, dh = nl & 63;
          int b = row >> 12, s = row & 4095;
          size_t bh = (size_t)(b * NHEAD + h);
          if (sec == 0)
            Qb[(bh * S_LEN + s) * DHEAD + dh] = f2bf(v);
          else if (sec == 1)
            Kb[(bh * S_LEN + s) * DHEAD + dh] = f2bf(v);
          else
            Vt[(bh * DHEAD + dh) * S_LEN + s] = f2bf(v);
        } else {
          Out[(size_t)row * DMODEL + col] = v;
        }
      }
}

// ---------------- causal flash attention (swapped-operand 32x32 structure) ----------------
// 2 waves x 32 q-rows = 64-row Q tile per block; KVB=64; S^T = mfma(K,Q) in-lane softmax;
// O^T = mfma(Vt, P^T); P packed via cvt_pk+permlane32_swap.
// grid 1024 = 16 bh x 64 q-tiles: 4 blocks/CU (128KB LDS), 8 waves/CU all co-resident.
// xcd = wgid&7 owns 2 heads (K/V 2MB, L2-resident); qt descending within XCD (LPT drain).
__global__ __launch_bounds__(128, 2)
void attn_k(const BF16* __restrict__ Qg, const BF16* __restrict__ Kg,
            const BF16* __restrict__ Vg, BF16* __restrict__ Og) {
  __shared__ BF16 Kl[2][64 * 64];
  __shared__ BF16 Vl[2][64 * 64];
  const int tid = threadIdx.x, l = tid & 63, w = tid >> 6;  // w in {0,1}
  const int hi = l >> 5, ln = l & 31;
  const int wgid = blockIdx.x;
  const int xcd = wgid & 7, j = wgid >> 3;  // j 0..127
  const int bh = xcd * 2 + (j & 1);         // 2 heads per XCD
  const int qt = 63 - (j >> 1);             // 64-row q-tile, descending (LPT)
  const int b = bh >> 3, h = bh & 7;
  const BF16* Qh = Qg + (size_t)bh * S_LEN * DHEAD;
  const BF16* Kh = Kg + (size_t)bh * S_LEN * DHEAD;
  const BF16* Vh = Vg + (size_t)bh * DHEAD * S_LEN;
  const float CS = 0.18033688011112042f;  // (1/sqrt(64)) * log2(e)

  const int NT = qt + 1;
  const int q0w = qt * 64 + w * 32;
  const int qrow = q0w + ln;

  // Q fragments (B-operand: col=q=l&31, k=dh=(l>>5)*8+j per 16-wide slice)
  short8 qb[4];
  {
    const BF16* qp = Qh + (size_t)qrow * DHEAD + hi * 8;
#pragma unroll
    for (int ks = 0; ks < 4; ++ks) qb[ks] = *(const short8*)(qp + ks * 16);
  }
  f32x16 oacc0 = {}, oacc1 = {};
  float m_ = -INFINITY, l_ = 0.f;

  auto stage = [&](int buf, int kt) {
    const int kv0 = kt * 64;
#pragma unroll
    for (int i = 0; i < 4; ++i) {
      int base = i * 2048 + w * 1024;
      int off = base + l * 16;
      int row = off >> 7;
      int slot = ((off >> 4) & 7) ^ (row & 7);
      gload16(Kh + (size_t)(kv0 + row) * DHEAD + slot * 8, (char*)Kl[buf] + base);
      gload16(Vh + (size_t)row * S_LEN + kv0 + slot * 8, (char*)Vl[buf] + base);
    }
  };
  int cur = 0;
  stage(cur, 0);

  for (int kt = 0; kt < NT; ++kt) {
    __syncthreads();  // buf[cur] staged; prior reads of buf[cur^1] done
    if (kt + 1 < NT) stage(cur ^ 1, kt + 1);
    const int kv0 = kt * 64;
    // --- QK^T: S^T[kv][q] ---
    const char* Kb_ = (const char*)Kl[cur];
    f32x16 s0 = {}, s1 = {};
    __builtin_amdgcn_s_setprio(1);
#pragma unroll
    for (int ks = 0; ks < 4; ++ks) {
      int slot0 = (2 * ks + hi) ^ (ln & 7);
      short8 kf0 = *(const short8*)(Kb_ + ln * 128 + slot0 * 16);
      int row1 = 32 + ln;
      int slot1 = (2 * ks + hi) ^ (row1 & 7);
      short8 kf1 = *(const short8*)(Kb_ + row1 * 128 + slot1 * 16);
      s0 = __builtin_amdgcn_mfma_f32_32x32x16_bf16(kf0, qb[ks], s0, 0, 0, 0);
      s1 = __builtin_amdgcn_mfma_f32_32x32x16_bf16(kf1, qb[ks], s1, 0, 0, 0);
    }
    __builtin_amdgcn_s_setprio(0);
    // --- causal mask on the diagonal tile ---
    if (kt == qt) {
#pragma unroll
      for (int r = 0; r < 16; ++r) {
        int crow = (r & 3) + 8 * (r >> 2) + 4 * hi;
        if (kv0 + crow > qrow) s0[r] = -INFINITY;
        if (kv0 + 32 + crow > qrow) s1[r] = -INFINITY;
      }
    }
    // --- in-lane online softmax (v_max3 tree) ---
    float a0 = MAX3(s0[0], s0[1], s0[2]);
    float a1 = MAX3(s0[3], s0[4], s0[5]);
    float a2 = MAX3(s0[6], s0[7], s0[8]);
    float a3 = MAX3(s0[9], s0[10], s0[11]);
    float a4 = MAX3(s0[12], s0[13], s0[14]);
    float a5 = MAX3(s0[15], s1[0], s1[1]);
    float a6 = MAX3(s1[2], s1[3], s1[4]);
    float a7 = MAX3(s1[5], s1[6], s1[7]);
    float a8 = MAX3(s1[8], s1[9], s1[10]);
    float a9 = MAX3(s1[11], s1[12], s1[13]);
    float a10 = fmaxf(s1[14], s1[15]);
    float b0 = MAX3(a0, a1, a2);
    float b1 = MAX3(a3, a4, a5);
    float b2 = MAX3(a6, a7, a8);
    float b3 = fmaxf(a9, a10);
    float pmax = fmaxf(fmaxf(b0, b1), fmaxf(b2, b3));
    pmax = fmaxf(pmax, partner32(pmax, hi));
    bool need = (pmax - m_) * CS > 8.0f;  // defer-max (T13)
    if (__any(need)) {
      float mn = fmaxf(m_, pmax);
      float alpha = exp2f((m_ - mn) * CS);
      m_ = mn;
      l_ *= alpha;
#pragma unroll
      for (int r = 0; r < 16; ++r) { oacc0[r] *= alpha; oacc1[r] *= alpha; }
    }
    const float mb = m_ * CS;
    float p0[16], p1[16];
    float rs = 0.f;
#pragma unroll
    for (int r = 0; r < 16; ++r) { p0[r] = exp2f(fmaf(s0[r], CS, -mb)); rs += p0[r]; }
#pragma unroll
    for (int r = 0; r < 16; ++r) { p1[r] = exp2f(fmaf(s1[r], CS, -mb)); rs += p1[r]; }
    rs += partner32(rs, hi);
    l_ += rs;
    // --- pack P into B-fragments (T12: cvt_pk + permlane32_swap) ---
    short8 pf[4];
#pragma unroll
    for (int half = 0; half < 2; ++half) {
      const float* pp = half ? p1 : p0;
      unsigned w01 = cvtpk(pp[0], pp[1]), w23 = cvtpk(pp[2], pp[3]);
      unsigned w45 = cvtpk(pp[4], pp[5]), w67 = cvtpk(pp[6], pp[7]);
      unsigned w89 = cvtpk(pp[8], pp[9]), wab = cvtpk(pp[10], pp[11]);
      unsigned wcd = cvtpk(pp[12], pp[13]), wef = cvtpk(pp[14], pp[15]);
      pl32(w01, w45);  // w01 -> dw0 {hi0:kv01,hi1:kv89}, w45 -> dw2
      pl32(w23, w67);  // w23 -> dw1, w67 -> dw3
      pl32(w89, wcd);
      pl32(wab, wef);
      union { uint4v u; short8 s; } c0, c1;
      c0.u = (uint4v){w01, w23, w45, w67};
      c1.u = (uint4v){w89, wab, wcd, wef};
      pf[half * 2 + 0] = c0.s;
      pf[half * 2 + 1] = c1.s;
    }
    // --- PV: O^T[dh][q] += V^T * P^T ---
    const char* Vb_ = (const char*)Vl[cur];
    __builtin_amdgcn_s_setprio(1);
#pragma unroll
    for (int ks = 0; ks < 4; ++ks) {
      int slot0 = (2 * ks + hi) ^ (ln & 7);
      short8 vf0 = *(const short8*)(Vb_ + ln * 128 + slot0 * 16);
      int row1 = 32 + ln;
      int slot1 = (2 * ks + hi) ^ (row1 & 7);
      short8 vf1 = *(const short8*)(Vb_ + row1 * 128 + slot1 * 16);
      oacc0 = __builtin_amdgcn_mfma_f32_32x32x16_bf16(vf0, pf[ks], oacc0, 0, 0, 0);
      oacc1 = __builtin_amdgcn_mfma_f32_32x32x16_bf16(vf1, pf[ks], oacc1, 0, 0, 0);
    }
    __builtin_amdgcn_s_setprio(0);
    cur ^= 1;
  }

  // epilogue: O[b][s][h*64+dh], lane owns q=ln for all dh quads
  float inv = 1.0f / l_;
#pragma unroll
  for (int blk = 0; blk < 2; ++blk) {
    const f32x16 oa = blk ? oacc1 : oacc0;
#pragma unroll
    for (int g = 0; g < 4; ++g) {
      int dh0 = 8 * g + 4 * hi + 32 * blk;
      unsigned lo = cvtpk(oa[4 * g + 0] * inv, oa[4 * g + 1] * inv);
      unsigned h2 = cvtpk(oa[4 * g + 2] * inv, oa[4 * g + 3] * inv);
      uint2v st = {lo, h2};
      *(uint2v*)(Og + ((size_t)(b * S_LEN + qrow)) * DMODEL + h * DHEAD + dh0) = st;
    }
  }
}

// ---------------- launch ----------------
extern "C" void kernel_launch(void* const* d_in, const int* in_sizes, int n_in,
                              void* d_out, int out_size, void* d_ws, size_t ws_size,
                              hipStream_t stream) {
  const float* x = (const float*)d_in[0];
  const float* W_in = (const float*)d_in[1];
  const float* b_in = (const float*)d_in[2];
  const float* W_out = (const float*)d_in[3];
  const float* b_out = (const float*)d_in[4];
  float* out = (float*)d_out;

  char* ws = (char*)d_ws;
  const size_t SZ_X = (size_t)BS * S_LEN * DMODEL * 2;
  BF16* xb    = (BF16*)(ws);
  BF16* wint  = (BF16*)(ws + SZ_X);
  BF16* woutt = (BF16*)(ws + SZ_X + 3 * DMODEL * DMODEL * 2);
  BF16* Qb    = (BF16*)(ws + SZ_X + 4 * DMODEL * DMODEL * 2);
  BF16* Kb    = (BF16*)((char*)Qb + SZ_X);
  BF16* Vt    = (BF16*)((char*)Kb + SZ_X);
  BF16* Ob    = (BF16*)((char*)Vt + SZ_X);

  cvt_x_k<<<dim3((BS * S_LEN * DMODEL) / 4 / 256), 256, 0, stream>>>(x, xb);
  tr_cvt_k<<<dim3(3 * DMODEL / 32, DMODEL / 32), 256, 0, stream>>>(W_in, wint, DMODEL, 3 * DMODEL);
  tr_cvt_k<<<dim3(DMODEL / 32, DMODEL / 32), 256, 0, stream>>>(W_out, woutt, DMODEL, DMODEL);
  gemm_k<0><<<dim3(BS * S_LEN / 128, 3 * DMODEL / 128), 256, 0, stream>>>(
      xb, wint, b_in, Qb, Kb, Vt, nullptr);
  attn_k<<<dim3(1024), 128, 0, stream>>>(Qb, Kb, Vt, Ob);
  gemm_k<1><<<dim3(BS * S_LEN / 128, DMODEL / 128), 256, 0, stream>>>(
      Ob, woutt, b_out, nullptr, nullptr, nullptr, out);
}

// Round 6
// 209.388 us; speedup vs baseline: 1.1423x; 1.1423x over previous
//
#include <hip/hip_runtime.h>
#include <cstdint>
#include <cmath>

typedef unsigned short BF16;
typedef __attribute__((ext_vector_type(8))) short short8;
typedef __attribute__((ext_vector_type(4))) float f32x4;
typedef __attribute__((ext_vector_type(16))) float f32x16;
typedef __attribute__((ext_vector_type(2))) unsigned int uint2v;
typedef __attribute__((ext_vector_type(4))) unsigned int uint4v;

#define S_LEN 4096
#define DMODEL 512
#define NHEAD 8
#define DHEAD 64
#define BS 2
#define NROWS (BS * NHEAD * S_LEN)  // 65536 (bh, s) rows

__device__ __forceinline__ BF16 f2bf(float f) {
  union { float f; uint32_t u; } v; v.f = f;
  uint32_t r = (v.u + 0x7FFFu + ((v.u >> 16) & 1u)) >> 16;
  return (BF16)r;
}

__device__ __forceinline__ unsigned cvtpk(float a, float b) {
  unsigned r;
  asm volatile("v_cvt_pk_bf16_f32 %0, %1, %2" : "=v"(r) : "v"(a), "v"(b));
  return r;
}

// value held by lane l^32 (permlane32_swap: vdst'=[lo|src_lo], vsrc'=[dst_hi|hi])
__device__ __forceinline__ float partner32(float x, int hi) {
  unsigned a = __float_as_uint(x), b = a;
  uint2v r = __builtin_amdgcn_permlane32_swap(a, b, false, false);
  return __uint_as_float(hi ? r[0] : r[1]);
}

// a' = [a_lo | b_lo], b' = [a_hi | b_hi]
__device__ __forceinline__ void pl32(unsigned &a, unsigned &b) {
  uint2v r = __builtin_amdgcn_permlane32_swap(a, b, false, false);
  a = r[0]; b = r[1];
}

__device__ __forceinline__ void gload16(const void* g, void* lds) {
  __builtin_amdgcn_global_load_lds(
      (const __attribute__((address_space(1))) void*)g,
      (__attribute__((address_space(3))) void*)lds, 16, 0, 0);
}

#define MAX3(a, b, c) fmaxf(fmaxf((a), (b)), (c))
#define CS_CONST 0.18033688011112042f  // (1/sqrt(64)) * log2(e)

// ---------------- convert x: fp32 -> bf16 ----------------
__global__ __launch_bounds__(256) void cvt_x_k(const float* __restrict__ x,
                                               BF16* __restrict__ xb) {
  int i = blockIdx.x * 256 + threadIdx.x;
  float4 v = reinterpret_cast<const float4*>(x)[i];
  ushort4 o;
  o.x = f2bf(v.x); o.y = f2bf(v.y); o.z = f2bf(v.z); o.w = f2bf(v.w);
  reinterpret_cast<ushort4*>(xb)[i] = o;
}

// ------------- transpose + convert: W (K x N) fp32 -> Wt (N x K) bf16 -------------
__global__ __launch_bounds__(256) void tr_cvt_k(const float* __restrict__ W,
                                                BF16* __restrict__ Wt,
                                                int K, int N) {
  __shared__ float t[32][33];
  int n0 = blockIdx.x * 32, k0 = blockIdx.y * 32;
  int tx = threadIdx.x & 31, ty = threadIdx.x >> 5;
#pragma unroll
  for (int i = 0; i < 4; ++i)
    t[ty + 8 * i][tx] = W[(size_t)(k0 + ty + 8 * i) * N + n0 + tx];
  __syncthreads();
#pragma unroll
  for (int i = 0; i < 4; ++i)
    Wt[(size_t)(n0 + ty + 8 * i) * K + k0 + tx] = f2bf(t[tx][ty + 8 * i]);
}

// ---------------- GEMM: C(128x128 tile) = A(M x 512) * Bt(N x 512)^T ----------------
template <int MODE>
__global__ __launch_bounds__(256)
void gemm_k(const BF16* __restrict__ A, const BF16* __restrict__ Bt,
            const float* __restrict__ bias,
            BF16* __restrict__ Qb, BF16* __restrict__ Kb, BF16* __restrict__ Vt,
            float* __restrict__ Out) {
  __shared__ BF16 As[128 * 64];
  __shared__ BF16 Bs[128 * 64];
  const int tid = threadIdx.x;
  const int l = tid & 63, w = tid >> 6;
  const int wm = w >> 1, wn = w & 1;
  const int bm = blockIdx.x, bn = blockIdx.y;
  f32x4 acc[4][4] = {};

  for (int kt = 0; kt < 512 / 64; ++kt) {
#pragma unroll
    for (int i = 0; i < 4; ++i) {
      int ldsoff = i * 4096 + w * 1024;
      int off = ldsoff + l * 16;
      int row = off >> 7;
      int slot = ((off >> 4) & 7) ^ (row & 7);
      gload16(A + (size_t)(bm * 128 + row) * 512 + kt * 64 + slot * 8,
              (char*)As + ldsoff);
      gload16(Bt + (size_t)(bn * 128 + row) * 512 + kt * 64 + slot * 8,
              (char*)Bs + ldsoff);
    }
    __syncthreads();
    const char* Ab = (const char*)As;
    const char* Bb = (const char*)Bs;
    short8 af[4][2], bfr[4][2];
#pragma unroll
    for (int mf = 0; mf < 4; ++mf)
#pragma unroll
      for (int kk = 0; kk < 2; ++kk) {
        int row = wm * 64 + mf * 16 + (l & 15);
        int slot = ((l >> 4) + 4 * kk) ^ (row & 7);
        af[mf][kk] = *(const short8*)(Ab + row * 128 + slot * 16);
      }
#pragma unroll
    for (int nf = 0; nf < 4; ++nf)
#pragma unroll
      for (int kk = 0; kk < 2; ++kk) {
        int row = wn * 64 + nf * 16 + (l & 15);
        int slot = ((l >> 4) + 4 * kk) ^ (row & 7);
        bfr[nf][kk] = *(const short8*)(Bb + row * 128 + slot * 16);
      }
    __builtin_amdgcn_s_setprio(1);
#pragma unroll
    for (int kk = 0; kk < 2; ++kk)
#pragma unroll
      for (int mf = 0; mf < 4; ++mf)
#pragma unroll
        for (int nf = 0; nf < 4; ++nf)
          acc[mf][nf] = __builtin_amdgcn_mfma_f32_16x16x32_bf16(
              af[mf][kk], bfr[nf][kk], acc[mf][nf], 0, 0, 0);
    __builtin_amdgcn_s_setprio(0);
    __syncthreads();
  }

#pragma unroll
  for (int mf = 0; mf < 4; ++mf)
#pragma unroll
    for (int nf = 0; nf < 4; ++nf)
#pragma unroll
      for (int r = 0; r < 4; ++r) {
        int row = bm * 128 + wm * 64 + mf * 16 + ((l >> 4) << 2) + r;
        int col = bn * 128 + wn * 64 + nf * 16 + (l & 15);
        float v = acc[mf][nf][r] + bias[col];
        if (MODE == 0) {
          int sec = col >> 9, nl = col & 511;
          int h = nl >> 6, dh = nl & 63;
          int b = row >> 12, s = row & 4095;
          size_t bh = (size_t)(b * NHEAD + h);
          if (sec == 0)
            Qb[(bh * S_LEN + s) * DHEAD + dh] = f2bf(v);
          else if (sec == 1)
            Kb[(bh * S_LEN + s) * DHEAD + dh] = f2bf(v);
          else
            Vt[(bh * DHEAD + dh) * S_LEN + s] = f2bf(v);
        } else {
          Out[(size_t)row * DMODEL + col] = v;
        }
      }
}

// ---------------- causal flash attention: uniform kv-split blocks ----------------
// 4 waves x 32 q-rows = 128-row Q tile; KVB=64; swapped-operand 32x32 MFMA; in-lane
// softmax; P packed via cvt_pk+permlane32_swap. Each q-tile qt needs 2qt+2 kv-steps,
// split into two halves of qt+1 steps; blocks pair tiles {p, 31-p} at the same half
// -> every block runs exactly 33 steps. 512 uniform blocks x 4 waves, 32KB LDS:
// 2 blocks/CU, 8 waves/CU resident for the whole dispatch (no tail).
// Partial (O,m,l) per half merged by merge_k.
__global__ __launch_bounds__(256, 2)
void attn_k(const BF16* __restrict__ Qg, const BF16* __restrict__ Kg,
            const BF16* __restrict__ Vg, float* __restrict__ Op0,
            float* __restrict__ Op1, float* __restrict__ Ml) {
  __shared__ BF16 Kl[2][64 * 64];
  __shared__ BF16 Vl[2][64 * 64];
  const int tid = threadIdx.x, l = tid & 63, w = tid >> 6;
  const int hi = l >> 5, ln = l & 31;
  const int wgid = blockIdx.x;
  const int xcd = wgid & 7, j = wgid >> 3;  // j 0..63
  const int bh = xcd * 2 + (j & 1);         // 2 heads per XCD (K/V L2-resident)
  const int half = (j >> 1) & 1;
  const int p = j >> 2;                     // pair index 0..15
  const BF16* Qh = Qg + (size_t)bh * S_LEN * DHEAD;
  const BF16* Kh = Kg + (size_t)bh * S_LEN * DHEAD;
  const BF16* Vh = Vg + (size_t)bh * DHEAD * S_LEN;
  const float CS = CS_CONST;

  int cur = 0;
  for (int rep = 0; rep < 2; ++rep) {
    const int qt = rep ? (31 - p) : p;
    const int kbase = half ? (qt + 1) : 0;  // kv-tile subrange start
    const int NT = qt + 1;                  // steps this rep
    const int q0w = qt * 128 + w * 32;
    const int qrow = q0w + ln;
    __syncthreads();  // prior rep's reads done before restaging

    // Q fragments (B-operand: col=q=l&31, k=dh=(l>>5)*8+j per 16-wide slice)
    short8 qb[4];
    {
      const BF16* qp = Qh + (size_t)qrow * DHEAD + hi * 8;
#pragma unroll
      for (int ks = 0; ks < 4; ++ks) qb[ks] = *(const short8*)(qp + ks * 16);
    }
    f32x16 oacc0 = {}, oacc1 = {};
    float m_ = -INFINITY, l_ = 0.f;

    auto stage = [&](int buf, int ktile) {
      const int kv0 = ktile * 64;
#pragma unroll
      for (int i = 0; i < 2; ++i) {
        int base = i * 4096 + w * 1024;
        int off = base + l * 16;
        int row = off >> 7;
        int slot = ((off >> 4) & 7) ^ (row & 7);
        gload16(Kh + (size_t)(kv0 + row) * DHEAD + slot * 8, (char*)Kl[buf] + base);
        gload16(Vh + (size_t)row * S_LEN + kv0 + slot * 8, (char*)Vl[buf] + base);
      }
    };
    stage(cur, kbase);

    for (int kt = 0; kt < NT; ++kt) {
      __syncthreads();  // buf[cur] staged; prior reads of buf[cur^1] done
      if (kt + 1 < NT) stage(cur ^ 1, kbase + kt + 1);
      const int kv0 = (kbase + kt) * 64;
      if (kv0 <= q0w + 31) {  // wave-uniform: skip fully-masked tile
        // --- QK^T: S^T[kv][q] ---
        const char* Kb_ = (const char*)Kl[cur];
        f32x16 s0 = {}, s1 = {};
        __builtin_amdgcn_s_setprio(1);
#pragma unroll
        for (int ks = 0; ks < 4; ++ks) {
          int slot0 = (2 * ks + hi) ^ (ln & 7);
          short8 kf0 = *(const short8*)(Kb_ + ln * 128 + slot0 * 16);
          int row1 = 32 + ln;
          int slot1 = (2 * ks + hi) ^ (row1 & 7);
          short8 kf1 = *(const short8*)(Kb_ + row1 * 128 + slot1 * 16);
          s0 = __builtin_amdgcn_mfma_f32_32x32x16_bf16(kf0, qb[ks], s0, 0, 0, 0);
          s1 = __builtin_amdgcn_mfma_f32_32x32x16_bf16(kf1, qb[ks], s1, 0, 0, 0);
        }
        __builtin_amdgcn_s_setprio(0);
        // --- causal mask on diagonal-overlap tiles ---
        if (kv0 + 63 > q0w) {
#pragma unroll
          for (int r = 0; r < 16; ++r) {
            int crow = (r & 3) + 8 * (r >> 2) + 4 * hi;
            if (kv0 + crow > qrow) s0[r] = -INFINITY;
            if (kv0 + 32 + crow > qrow) s1[r] = -INFINITY;
          }
        }
        // --- in-lane online softmax (v_max3 tree) ---
        float a0 = MAX3(s0[0], s0[1], s0[2]);
        float a1 = MAX3(s0[3], s0[4], s0[5]);
        float a2 = MAX3(s0[6], s0[7], s0[8]);
        float a3 = MAX3(s0[9], s0[10], s0[11]);
        float a4 = MAX3(s0[12], s0[13], s0[14]);
        float a5 = MAX3(s0[15], s1[0], s1[1]);
        float a6 = MAX3(s1[2], s1[3], s1[4]);
        float a7 = MAX3(s1[5], s1[6], s1[7]);
        float a8 = MAX3(s1[8], s1[9], s1[10]);
        float a9 = MAX3(s1[11], s1[12], s1[13]);
        float a10 = fmaxf(s1[14], s1[15]);
        float b0 = MAX3(a0, a1, a2);
        float b1 = MAX3(a3, a4, a5);
        float b2 = MAX3(a6, a7, a8);
        float b3 = fmaxf(a9, a10);
        float pmax = fmaxf(fmaxf(b0, b1), fmaxf(b2, b3));
        pmax = fmaxf(pmax, partner32(pmax, hi));
        bool need = (pmax - m_) * CS > 8.0f;  // defer-max (T13)
        if (__any(need)) {
          float mn = fmaxf(m_, pmax);
          float alpha = exp2f((m_ - mn) * CS);
          m_ = mn;
          l_ *= alpha;
#pragma unroll
          for (int r = 0; r < 16; ++r) { oacc0[r] *= alpha; oacc1[r] *= alpha; }
        }
        const float mb = m_ * CS;
        float p0[16], p1[16];
        float rs = 0.f;
#pragma unroll
        for (int r = 0; r < 16; ++r) { p0[r] = exp2f(fmaf(s0[r], CS, -mb)); rs += p0[r]; }
#pragma unroll
        for (int r = 0; r < 16; ++r) { p1[r] = exp2f(fmaf(s1[r], CS, -mb)); rs += p1[r]; }
        rs += partner32(rs, hi);
        l_ += rs;
        // --- pack P into B-fragments (T12: cvt_pk + permlane32_swap) ---
        short8 pf[4];
#pragma unroll
        for (int hf = 0; hf < 2; ++hf) {
          const float* pp = hf ? p1 : p0;
          unsigned w01 = cvtpk(pp[0], pp[1]), w23 = cvtpk(pp[2], pp[3]);
          unsigned w45 = cvtpk(pp[4], pp[5]), w67 = cvtpk(pp[6], pp[7]);
          unsigned w89 = cvtpk(pp[8], pp[9]), wab = cvtpk(pp[10], pp[11]);
          unsigned wcd = cvtpk(pp[12], pp[13]), wef = cvtpk(pp[14], pp[15]);
          pl32(w01, w45);  // w01 -> dw0 {hi0:kv01,hi1:kv89}, w45 -> dw2
          pl32(w23, w67);  // w23 -> dw1, w67 -> dw3
          pl32(w89, wcd);
          pl32(wab, wef);
          union { uint4v u; short8 s; } c0, c1;
          c0.u = (uint4v){w01, w23, w45, w67};
          c1.u = (uint4v){w89, wab, wcd, wef};
          pf[hf * 2 + 0] = c0.s;
          pf[hf * 2 + 1] = c1.s;
        }
        // --- PV: O^T[dh][q] += V^T * P^T ---
        const char* Vb_ = (const char*)Vl[cur];
        __builtin_amdgcn_s_setprio(1);
#pragma unroll
        for (int ks = 0; ks < 4; ++ks) {
          int slot0 = (2 * ks + hi) ^ (ln & 7);
          short8 vf0 = *(const short8*)(Vb_ + ln * 128 + slot0 * 16);
          int row1 = 32 + ln;
          int slot1 = (2 * ks + hi) ^ (row1 & 7);
          short8 vf1 = *(const short8*)(Vb_ + row1 * 128 + slot1 * 16);
          oacc0 = __builtin_amdgcn_mfma_f32_32x32x16_bf16(vf0, pf[ks], oacc0, 0, 0, 0);
          oacc1 = __builtin_amdgcn_mfma_f32_32x32x16_bf16(vf1, pf[ks], oacc1, 0, 0, 0);
        }
        __builtin_amdgcn_s_setprio(0);
      }
      cur ^= 1;
    }

    // partial epilogue: raw O (un-normalized) f32 + (m,l) per row
    float* Op = half ? Op1 : Op0;
    const size_t rowbase = ((size_t)bh * S_LEN + qrow) * DHEAD;
#pragma unroll
    for (int blk = 0; blk < 2; ++blk) {
      const f32x16 oa = blk ? oacc1 : oacc0;
#pragma unroll
      for (int g = 0; g < 4; ++g) {
        int dh0 = 8 * g + 4 * hi + 32 * blk;
        float4 st = {oa[4 * g + 0], oa[4 * g + 1], oa[4 * g + 2], oa[4 * g + 3]};
        *(float4*)(Op + rowbase + dh0) = st;
      }
    }
    if (hi == 0) {
      float2 ml = {m_, l_};
      *(float2*)(Ml + ((size_t)half * NROWS + (size_t)bh * S_LEN + qrow) * 2) = ml;
    }
  }
}

// ---------------- merge partial halves -> Ob (bf16, head-merged layout) ----------------
// wave handles 64 rows, lane = dh. Ob[b][s][h*64+dh].
__global__ __launch_bounds__(256)
void merge_k(const float* __restrict__ Op0, const float* __restrict__ Op1,
             const float* __restrict__ Ml, BF16* __restrict__ Ob) {
  const int wv = blockIdx.x * 4 + (threadIdx.x >> 6);  // 0..1023
  const int lane = threadIdx.x & 63;
  const int row0 = wv * 64;
  for (int r = 0; r < 64; ++r) {
    int row = row0 + r;  // bh*4096 + s
    float2 ml1 = *(const float2*)(Ml + (size_t)row * 2);
    float2 ml2 = *(const float2*)(Ml + ((size_t)NROWS + row) * 2);
    float m = fmaxf(ml1.x, ml2.x);
    float a1 = exp2f((ml1.x - m) * CS_CONST);
    float a2 = exp2f((ml2.x - m) * CS_CONST);
    float linv = 1.0f / (ml1.y * a1 + ml2.y * a2);
    float o = (Op0[(size_t)row * 64 + lane] * a1 +
               Op1[(size_t)row * 64 + lane] * a2) * linv;
    int bh = row >> 12, s = row & 4095;
    Ob[((size_t)((bh >> 3) * S_LEN + s)) * DMODEL + (bh & 7) * DHEAD + lane] = f2bf(o);
  }
}

// ---------------- launch ----------------
extern "C" void kernel_launch(void* const* d_in, const int* in_sizes, int n_in,
                              void* d_out, int out_size, void* d_ws, size_t ws_size,
                              hipStream_t stream) {
  const float* x = (const float*)d_in[0];
  const float* W_in = (const float*)d_in[1];
  const float* b_in = (const float*)d_in[2];
  const float* W_out = (const float*)d_in[3];
  const float* b_out = (const float*)d_in[4];
  float* out = (float*)d_out;

  char* ws = (char*)d_ws;
  const size_t SZ_X = (size_t)BS * S_LEN * DMODEL * 2;      // 8 MB bf16 tensor
  const size_t SZ_OP = (size_t)NROWS * DHEAD * 4;           // 16.78 MB f32 partial
  BF16* xb    = (BF16*)(ws);
  BF16* wint  = (BF16*)(ws + SZ_X);
  BF16* woutt = (BF16*)(ws + SZ_X + 3 * DMODEL * DMODEL * 2);
  BF16* Qb    = (BF16*)(ws + SZ_X + 4 * DMODEL * DMODEL * 2);
  BF16* Kb    = (BF16*)((char*)Qb + SZ_X);
  BF16* Vt    = (BF16*)((char*)Kb + SZ_X);
  BF16* Ob    = (BF16*)((char*)Vt + SZ_X);
  float* Op0  = (float*)((char*)Ob + SZ_X);
  float* Op1  = (float*)((char*)Op0 + SZ_OP);
  float* Ml   = (float*)((char*)Op1 + SZ_OP);  // 2 * NROWS * float2

  cvt_x_k<<<dim3((BS * S_LEN * DMODEL) / 4 / 256), 256, 0, stream>>>(x, xb);
  tr_cvt_k<<<dim3(3 * DMODEL / 32, DMODEL / 32), 256, 0, stream>>>(W_in, wint, DMODEL, 3 * DMODEL);
  tr_cvt_k<<<dim3(DMODEL / 32, DMODEL / 32), 256, 0, stream>>>(W_out, woutt, DMODEL, DMODEL);
  gemm_k<0><<<dim3(BS * S_LEN / 128, 3 * DMODEL / 128), 256, 0, stream>>>(
      xb, wint, b_in, Qb, Kb, Vt, nullptr);
  attn_k<<<dim3(512), 256, 0, stream>>>(Qb, Kb, Vt, Op0, Op1, Ml);
  merge_k<<<dim3(256), 256, 0, stream>>>(Op0, Op1, Ml, Ob);
  gemm_k<1><<<dim3(BS * S_LEN / 128, DMODEL / 128), 256, 0, stream>>>(
      Ob, woutt, b_out, nullptr, nullptr, nullptr, out);
}